// Round 1
// baseline (15158.279 us; speedup 1.0000x reference)
//
#include <hip/hip_runtime.h>
#include <hip/hip_bf16.h>

// ---------------------------------------------------------------------------
// BiLSTM (bf16 MFMA, fused input+recurrent GEMM per step) + CRF forward.
// Sizes fixed by the problem:
constexpr int B_ = 64, S_ = 512, E_ = 300, H_ = 512, T_ = 12;
constexpr int G4 = 4 * H_;          // 2048 gate rows
constexpr int KPADX = 320;          // E padded to 320 (zeros 300..319)
constexpr int KTOT = KPADX + H_;    // 832 total K (x | h)
constexpr int KC_TOT = KTOT / 32;   // 26 MFMA k-chunks
constexpr int NT16 = G4 / 16;       // 128 16-wide n tiles
constexpr float NEGV = -10000.0f;
// START = T-2 = 10, STOP = T-1 = 11

typedef __attribute__((ext_vector_type(8))) short bf16x8_t;
typedef __attribute__((ext_vector_type(4))) float f32x4_t;

// ---- workspace layout (bytes) ---------------------------------------------
constexpr size_t WC_OFF = 0;
constexpr size_t WC_BYTES = (size_t)2 * NT16 * KC_TOT * 64 * 8 * 2;  // 6,815,744
constexpr size_t HH_OFF = WC_OFF + WC_BYTES;
constexpr size_t HH_BYTES = (size_t)2 * (S_ + 1) * B_ * H_ * 2;      // 67,239,936
constexpr size_t CS_OFF = HH_OFF + HH_BYTES;
constexpr size_t CS_BYTES = (size_t)2 * B_ * H_ * 4;                 // 262,144
constexpr size_t FE_OFF = CS_OFF + CS_BYTES;
constexpr size_t FE_BYTES = (size_t)S_ * B_ * T_ * 4;                // 1,572,864
constexpr size_t LSE_OFF = FE_OFF + FE_BYTES;

// ---------------------------------------------------------------------------
// prep: (1) combined weights [W_ih | pad | W_hh] -> bf16 in MFMA B-fragment
// order: [dir][tile16][kchunk][lane][8], with gate-interleaved row permutation
// j' : tile16 tt = nt*4 + gate, col-in-tile = hl  ->  original row
// j = gate*H + nt*16 + hl.  (2) h0 -> bf16 h_hist slot 0. (3) c0 -> c_state.
__global__ void prep_kernel(const float* __restrict__ Wih_f, const float* __restrict__ Whh_f,
                            const float* __restrict__ Wih_b, const float* __restrict__ Whh_b,
                            const float* __restrict__ h0, const float* __restrict__ c0,
                            char* __restrict__ ws) {
  __hip_bfloat16* wc = (__hip_bfloat16*)(ws + WC_OFF);
  __hip_bfloat16* hh = (__hip_bfloat16*)(ws + HH_OFF);
  float* cs = (float*)(ws + CS_OFF);
  const int WCN = 2 * NT16 * KC_TOT * 64;  // 425,984
  int idx = blockIdx.x * 256 + threadIdx.x;
  if (idx < WCN) {
    int lane = idx & 63;
    int r = idx >> 6;
    int kc = r % KC_TOT; r /= KC_TOT;
    int tt = r % NT16;
    int dir = r / NT16;
    int n16 = lane & 15, quad = lane >> 4;
    int nt = tt >> 2, gate = tt & 3;
    int j = gate * H_ + nt * 16 + n16;   // original gate row
    int k0 = kc * 32 + quad * 8;
    const float* Wih = dir ? Wih_b : Wih_f;
    const float* Whh = dir ? Whh_b : Whh_f;
    __hip_bfloat16* dst = wc + (size_t)idx * 8;
    #pragma unroll
    for (int jj = 0; jj < 8; jj++) {
      int k = k0 + jj;
      float f;
      if (k < E_) f = Wih[(size_t)j * E_ + k];
      else if (k < KPADX) f = 0.f;
      else f = Whh[(size_t)j * H_ + (k - KPADX)];
      dst[jj] = __float2bfloat16(f);
    }
  } else if (idx < WCN + 2 * B_ * H_) {
    int i = idx - WCN;                       // dir*B*H + b*H + h
    int dir = i / (B_ * H_), rem = i % (B_ * H_);
    hh[(size_t)dir * (S_ + 1) * B_ * H_ + rem] = __float2bfloat16(h0[i]);
  } else if (idx < WCN + 4 * B_ * H_) {
    int i = idx - WCN - 2 * B_ * H_;
    cs[i] = c0[i];
  }
}

// ---------------------------------------------------------------------------
// One LSTM time-step, both directions.  grid = 64 blocks (dir 2 x ntile 32),
// block = 256.  Block (dir, nt) computes gates for h-range [nt*16, nt*16+16),
// all 4 gates (one per wave), all 64 batch rows, then does the c/h update.
// A = [x_spos | h_prev] staged to LDS bf16 in two K-halves (pool 54.3 KB).
__launch_bounds__(256)
__global__ void step_kernel(int s, const int* __restrict__ tokens,
                            const float* __restrict__ Wemb,
                            const float* __restrict__ bias_f,
                            const float* __restrict__ bias_b,
                            char* __restrict__ ws) {
  __shared__ short pool[64 * 424];   // 54,272 B; A-tile, then g-exchange overlay
  const int dir = blockIdx.x >> 5;
  const int nt = blockIdx.x & 31;
  const int tid = threadIdx.x;
  const __hip_bfloat16* wc = (const __hip_bfloat16*)(ws + WC_OFF);
  __hip_bfloat16* hh = (__hip_bfloat16*)(ws + HH_OFF);
  float* cs = (float*)(ws + CS_OFF);
  const int spos = dir ? (S_ - 1 - s) : s;
  const __hip_bfloat16* hprev = hh + (size_t)(dir * (S_ + 1) + s) * B_ * H_;

  f32x4_t acc[4];
  #pragma unroll
  for (int i = 0; i < 4; i++) acc[i] = (f32x4_t)(0.f);

  const int lane = tid & 63, wv = tid >> 6;
  const int quad = lane >> 4, l16 = lane & 15;

  for (int half = 0; half < 2; half++) {
    __syncthreads();
    const int kbase = half * 416;
    // stage A cols [kbase, kbase+416) as bf16, row stride 424 (bank-safe)
    for (int i = tid; i < 64 * 52; i += 256) {
      int row = i / 52, c8 = i % 52;
      int kg = kbase + c8 * 8;
      short* dst = pool + row * 424 + c8 * 8;
      if (kg >= KPADX) {
        *(uint4*)dst = *(const uint4*)(hprev + (size_t)row * H_ + (kg - KPADX));
      } else {
        const float* src = Wemb + (size_t)tokens[row * S_ + spos] * E_;
        __hip_bfloat16* d = (__hip_bfloat16*)dst;
        if (kg + 7 < E_) {
          float4 f0 = *(const float4*)(src + kg);
          float4 f1 = *(const float4*)(src + kg + 4);
          d[0] = __float2bfloat16(f0.x); d[1] = __float2bfloat16(f0.y);
          d[2] = __float2bfloat16(f0.z); d[3] = __float2bfloat16(f0.w);
          d[4] = __float2bfloat16(f1.x); d[5] = __float2bfloat16(f1.y);
          d[6] = __float2bfloat16(f1.z); d[7] = __float2bfloat16(f1.w);
        } else {
          #pragma unroll
          for (int j = 0; j < 8; j++) {
            int k = kg + j;
            d[j] = __float2bfloat16(k < E_ ? src[k] : 0.f);
          }
        }
      }
    }
    __syncthreads();
    // MFMA K-loop over this half (13 k-chunks of 32)
    for (int kci = 0; kci < 13; kci++) {
      int kc = half * 13 + kci;
      size_t boff = (((size_t)dir * NT16 + (nt * 4 + wv)) * KC_TOT + kc) * 64 + lane;
      bf16x8_t bfrag = *(const bf16x8_t*)(wc + boff * 8);
      int colbase = kci * 32 + quad * 8;
      #pragma unroll
      for (int mf = 0; mf < 4; mf++) {
        bf16x8_t afrag = *(const bf16x8_t*)(pool + (mf * 16 + l16) * 424 + colbase);
        acc[mf] = __builtin_amdgcn_mfma_f32_16x16x32_bf16(afrag, bfrag, acc[mf], 0, 0, 0);
      }
    }
  }
  __syncthreads();
  // exchange gates through LDS: wave wv holds gate wv; C/D: col=l16 (=hl),
  // row = mf*16 + quad*4 + reg (= batch b)
  float* gl = (float*)pool;  // [gate][64][17]
  #pragma unroll
  for (int mf = 0; mf < 4; mf++)
    #pragma unroll
    for (int r = 0; r < 4; r++) {
      int m = mf * 16 + quad * 4 + r;
      gl[(wv * 64 + m) * 17 + l16] = acc[mf][r];
    }
  __syncthreads();
  // elementwise LSTM cell update for (b, hl) pairs
  const float* bias = dir ? bias_b : bias_f;
  for (int it = 0; it < 4; it++) {
    int item = tid + it * 256;          // item = b*16 + hl
    int b = item >> 4, hl = item & 15;
    int hg = nt * 16 + hl;
    float gi = gl[(0 * 64 + b) * 17 + hl] + bias[0 * H_ + hg];
    float gf = gl[(1 * 64 + b) * 17 + hl] + bias[1 * H_ + hg];
    float gg = gl[(2 * 64 + b) * 17 + hl] + bias[2 * H_ + hg];
    float go = gl[(3 * 64 + b) * 17 + hl] + bias[3 * H_ + hg];
    float ii = 1.f / (1.f + __expf(-gi));
    float ff = 1.f / (1.f + __expf(-gf));
    float gt = 1.f - 2.f / (1.f + __expf(2.f * gg));   // tanh
    float oo = 1.f / (1.f + __expf(-go));
    size_t cidx = ((size_t)dir * B_ + b) * H_ + hg;
    float c = ff * cs[cidx] + ii * gt;
    cs[cidx] = c;
    float hv = oo * (1.f - 2.f / (1.f + __expf(2.f * c)));
    hh[((size_t)(dir * (S_ + 1) + s + 1) * B_ + b) * H_ + hg] = __float2bfloat16(hv);
  }
}

// ---------------------------------------------------------------------------
// feats[s,b,t] = [hf(s) | hb(s)] . W_out[t,:] + b_out[t].  block per s.
__launch_bounds__(256)
__global__ void feats_kernel(const float* __restrict__ Wout,
                             const float* __restrict__ bout,
                             char* __restrict__ ws) {
  __shared__ float wl[12 * 1024];   // 48 KB
  const int s = blockIdx.x, tid = threadIdx.x;
  for (int i = tid; i < 12 * 1024 / 4; i += 256)
    *(float4*)(wl + i * 4) = *(const float4*)(Wout + i * 4);
  __syncthreads();
  const __hip_bfloat16* hh = (const __hip_bfloat16*)(ws + HH_OFF);
  float* fe = (float*)(ws + FE_OFF);
  int b = tid >> 2, tg = tid & 3, t0 = tg * 3;
  const __hip_bfloat16* hf = hh + (size_t)(0 * (S_ + 1) + s + 1) * B_ * H_ + (size_t)b * H_;
  const __hip_bfloat16* hb = hh + (size_t)(1 * (S_ + 1) + (S_ - s)) * B_ * H_ + (size_t)b * H_;
  float a0 = 0.f, a1 = 0.f, a2 = 0.f;
  for (int half = 0; half < 2; half++) {
    const __hip_bfloat16* hp = half ? hb : hf;
    int wof = half * 512;
    for (int k = 0; k < 512; k += 8) {
      uint4 raw = *(const uint4*)(hp + k);
      const __hip_bfloat16* hv = (const __hip_bfloat16*)&raw;
      float hfl[8];
      #pragma unroll
      for (int j = 0; j < 8; j++) hfl[j] = __bfloat162float(hv[j]);
      #pragma unroll
      for (int j = 0; j < 8; j++) {
        a0 += hfl[j] * wl[(t0 + 0) * 1024 + wof + k + j];
        a1 += hfl[j] * wl[(t0 + 1) * 1024 + wof + k + j];
        a2 += hfl[j] * wl[(t0 + 2) * 1024 + wof + k + j];
      }
    }
  }
  float* o = fe + ((size_t)s * B_ + b) * T_;
  o[t0 + 0] = a0 + bout[t0 + 0];
  o[t0 + 1] = a1 + bout[t0 + 1];
  o[t0 + 2] = a2 + bout[t0 + 2];
}

// ---------------------------------------------------------------------------
// CRF forward scan: one wave per batch element; lane = next-tag (<12).
__launch_bounds__(64)
__global__ void crf_kernel(const int* __restrict__ lengths,
                           const float* __restrict__ trans,
                           char* __restrict__ ws) {
  const int b = blockIdx.x, lane = threadIdx.x;
  const float* fe = (const float*)(ws + FE_OFF);
  float* lse = (float*)(ws + LSE_OFF);
  float tr[12];
  #pragma unroll
  for (int p = 0; p < 12; p++) tr[p] = (lane < 12) ? trans[lane * 12 + p] : 0.f;
  float tstop = (lane < 12) ? trans[11 * 12 + lane] : 0.f;  // STOP row
  float alpha = (lane == 10) ? 0.f : NEGV;                  // START tag
  const int len = lengths[b];
  for (int s = 0; s < S_; s++) {
    float feat = (lane < 12) ? fe[((size_t)s * B_ + b) * T_ + lane] : 0.f;
    float av[12];
    #pragma unroll
    for (int p = 0; p < 12; p++) av[p] = __shfl(alpha, p, 64) + tr[p];
    float mx = av[0];
    #pragma unroll
    for (int p = 1; p < 12; p++) mx = fmaxf(mx, av[p]);
    float sum = 0.f;
    #pragma unroll
    for (int p = 0; p < 12; p++) sum += __expf(av[p] - mx);
    float nw = mx + __logf(sum) + feat;
    if (s < len && lane < 12) alpha = nw;
  }
  float tv = (lane < 12) ? (alpha + tstop) : -3.0e38f;
  float mx = tv;
  #pragma unroll
  for (int off = 32; off > 0; off >>= 1) mx = fmaxf(mx, __shfl_xor(mx, off, 64));
  float sum = __expf(tv - mx);
  #pragma unroll
  for (int off = 32; off > 0; off >>= 1) sum += __shfl_xor(sum, off, 64);
  if (lane == 0) lse[b] = mx + __logf(sum);
}

__global__ void final_kernel(char* __restrict__ ws, float* __restrict__ out) {
  const float* lse = (const float*)(ws + LSE_OFF);
  float v = lse[threadIdx.x];
  #pragma unroll
  for (int off = 32; off > 0; off >>= 1) v += __shfl_xor(v, off, 64);
  if (threadIdx.x == 0) out[0] = v * (1.f / 64.f);
}

// ---------------------------------------------------------------------------
extern "C" void kernel_launch(void* const* d_in, const int* in_sizes, int n_in,
                              void* d_out, int out_size, void* d_ws, size_t ws_size,
                              hipStream_t stream) {
  (void)in_sizes; (void)n_in; (void)out_size; (void)ws_size;
  const int* tokens = (const int*)d_in[0];
  const int* lengths = (const int*)d_in[1];
  const float* Wemb = (const float*)d_in[2];
  const float* Wih_f = (const float*)d_in[3];
  const float* Whh_f = (const float*)d_in[4];
  const float* b_f = (const float*)d_in[5];
  const float* Wih_b = (const float*)d_in[6];
  const float* Whh_b = (const float*)d_in[7];
  const float* b_b = (const float*)d_in[8];
  const float* h0 = (const float*)d_in[9];
  const float* c0 = (const float*)d_in[10];
  const float* Wout = (const float*)d_in[11];
  const float* bout = (const float*)d_in[12];
  const float* trans = (const float*)d_in[13];
  char* ws = (char*)d_ws;
  float* out = (float*)d_out;

  int prep_items = 2 * NT16 * KC_TOT * 64 + 4 * B_ * H_;
  hipLaunchKernelGGL(prep_kernel, dim3((prep_items + 255) / 256), dim3(256), 0, stream,
                     Wih_f, Whh_f, Wih_b, Whh_b, h0, c0, ws);
  for (int s = 0; s < S_; s++)
    hipLaunchKernelGGL(step_kernel, dim3(64), dim3(256), 0, stream,
                       s, tokens, Wemb, b_f, b_b, ws);
  hipLaunchKernelGGL(feats_kernel, dim3(S_), dim3(256), 0, stream, Wout, bout, ws);
  hipLaunchKernelGGL(crf_kernel, dim3(B_), dim3(64), 0, stream, lengths, trans, ws);
  hipLaunchKernelGGL(final_kernel, dim3(1), dim3(64), 0, stream, ws, out);
}